// Round 5
// baseline (439.321 us; speedup 1.0000x reference)
//
#include <hip/hip_runtime.h>
#include <math.h>

#define BB 256
#define PP 16
#define LL 4
#define EE 128
#define NPATH (BB*PP)     // 4096
#define NMOD 512
#define CC1 512
#define CC2 256

// ---------------- workspace layout ----------------
// fast path: Wt [512][16][128][8] bf16 = 16 MB at 0
// fallback:  feat [4096][256] f32 = 4 MB at 16 MB
#define WS_WT     0
#define WS_FEAT   ((size_t)NMOD*EE*EE*2)                  // 16 MB
#define WS_END    (WS_FEAT + (size_t)NPATH*2*EE*4)        // 20 MB

__device__ __forceinline__ unsigned short f2bf(float f) {
    unsigned u = __float_as_uint(f);
    u = (u + 0x7fffu + ((u >> 16) & 1u)) >> 16;   // round-to-nearest-even
    return (unsigned short)u;
}
__device__ __forceinline__ float bf2f(unsigned short s) {
    return __uint_as_float(((unsigned)s) << 16);
}

// ---------------- W -> bf16 transpose-convert ------------------------------
// Wt[mid][kc][o][j] bf16, k = kc*8+j. Consumer lane o reading chunk kc hits
// Wt[(mid*16+kc)*128+o] -> 64 lanes = one contiguous 1 KB transaction.
__global__ __launch_bounds__(256) void k_wtrans(
    const float* __restrict__ W, unsigned short* __restrict__ Wt)
{
    const int tid = blockIdx.x*256 + threadIdx.x;     // 512*16*128 threads
    const int o   = tid & 127;
    const int kc  = (tid >> 7) & 15;
    const int mid = tid >> 11;
    const float* src = W + ((size_t)mid*EE + o)*EE + kc*8;
    const float4 a = *(const float4*)(src);
    const float4 b = *(const float4*)(src + 4);
    uint4 u;
    u.x = (unsigned)f2bf(a.x) | ((unsigned)f2bf(a.y) << 16);
    u.y = (unsigned)f2bf(a.z) | ((unsigned)f2bf(a.w) << 16);
    u.z = (unsigned)f2bf(b.x) | ((unsigned)f2bf(b.y) << 16);
    u.w = (unsigned)f2bf(b.z) | ((unsigned)f2bf(b.w) << 16);
    *(uint4*)(Wt + (size_t)tid*8) = u;
}

// ---------------- fully-fused per-batch-row kernel -------------------------
// Block b owns batch row b: 16 paths seeded into LDS, 4 chain steps (4 paths
// in flight, thread o does both x and y chains off one shared Wt read),
// then pool + 3-layer MLP entirely in-block. Removes the chain->mlp dispatch
// boundary, the 8 MB feat round-trip, and spreads MLP weight streaming over
// all 256 CUs (k_mlp used only 128 blocks).
__global__ __launch_bounds__(512) void k_row(
    const int* __restrict__ start_ids, const int* __restrict__ end_ids,
    const int* __restrict__ module_ids, const int* __restrict__ counts,
    const float* __restrict__ embed, const unsigned short* __restrict__ Wt,
    const float* __restrict__ bvec,
    const float* __restrict__ W1, const float* __restrict__ b1,
    const float* __restrict__ W2, const float* __restrict__ b2,
    const float* __restrict__ W3, const float* __restrict__ b3,
    float* __restrict__ out)
{
    const int t = threadIdx.x;       // 0..511
    const int b = blockIdx.x;        // batch row
    __shared__ float sx[2][PP][EE];  // 16 KB
    __shared__ float sy[2][PP][EE];  // 16 KB
    __shared__ float pl[256];
    __shared__ float h1s[CC1];
    __shared__ float h2p[2][CC2];
    __shared__ float red[256];

    // seed 16 paths (coalesced 512 B per embed row)
    for (int i = t; i < PP*EE; i += 512) {
        const int p = i >> 7, o = i & 127;
        sx[0][p][o] = embed[(size_t)start_ids[b*PP + p]*EE + o];
        sy[0][p][o] = embed[(size_t)end_ids[b*PP + p]*EE + o];
    }
    __syncthreads();

    // chain: 4 paths concurrent; thread (pg,o) does x[o],y[o] of path pi+pg
    const int pg = t >> 7, o = t & 127;
    int cur = 0;
    for (int l = 0; l < LL; ++l) {
        for (int pi = 0; pi < PP; pi += 4) {
            const int p   = pi + pg;
            const int mid = module_ids[(b*PP + p)*LL + l];
            float ax = bvec[(size_t)mid*EE + o];
            float ay = ax;
            const uint4*  wt  = (const uint4*)(Wt + (size_t)mid*16384);
            const float4* xv4 = (const float4*)sx[cur][p];
            const float4* yv4 = (const float4*)sy[cur][p];
            #pragma unroll 8
            for (int kc = 0; kc < 16; ++kc) {
                const uint4 wv = wt[kc*128 + o];          // coalesced 1 KB/wave
                const float4 xv0 = xv4[kc*2],   yv0 = yv4[kc*2];
                const float4 xv1 = xv4[kc*2+1], yv1 = yv4[kc*2+1];
                const float w0 = bf2f((unsigned short)(wv.x & 0xffffu));
                const float w1 = bf2f((unsigned short)(wv.x >> 16));
                const float w2 = bf2f((unsigned short)(wv.y & 0xffffu));
                const float w3 = bf2f((unsigned short)(wv.y >> 16));
                const float w4 = bf2f((unsigned short)(wv.z & 0xffffu));
                const float w5 = bf2f((unsigned short)(wv.z >> 16));
                const float w6 = bf2f((unsigned short)(wv.w & 0xffffu));
                const float w7 = bf2f((unsigned short)(wv.w >> 16));
                ax = fmaf(w0, xv0.x, ax); ay = fmaf(w0, yv0.x, ay);
                ax = fmaf(w1, xv0.y, ax); ay = fmaf(w1, yv0.y, ay);
                ax = fmaf(w2, xv0.z, ax); ay = fmaf(w2, yv0.z, ay);
                ax = fmaf(w3, xv0.w, ax); ay = fmaf(w3, yv0.w, ay);
                ax = fmaf(w4, xv1.x, ax); ay = fmaf(w4, yv1.x, ay);
                ax = fmaf(w5, xv1.y, ax); ay = fmaf(w5, yv1.y, ay);
                ax = fmaf(w6, xv1.z, ax); ay = fmaf(w6, yv1.z, ay);
                ax = fmaf(w7, xv1.w, ax); ay = fmaf(w7, yv1.w, ay);
            }
            sx[cur^1][p][o] = ax;
            sy[cur^1][p][o] = ay;
        }
        __syncthreads();
        cur ^= 1;
    }

    // pooling (same accumulation order as proven k_mlp)
    if (t < 256) {
        float acc = 0.f, cs = 0.f;
        #pragma unroll
        for (int p = 0; p < PP; ++p) {
            const float cc = (float)counts[b*PP + p];
            cs += cc;
            const float v = (t < 128) ? sx[cur][p][t] : sy[cur][p][t - 128];
            acc = fmaf(cc, v, acc);
        }
        pl[t] = acc / cs;
    }
    __syncthreads();

    // h1: thread t -> col t (512 cols)
    {
        const float4* w4 = (const float4*)(W1 + (size_t)t*256);
        float a = b1[t];
        for (int q = 0; q < 64; ++q) {
            const float4 wv = w4[q];
            const float4 v  = ((const float4*)pl)[q];
            a = fmaf(wv.x,v.x, fmaf(wv.y,v.y, fmaf(wv.z,v.z, fmaf(wv.w,v.w, a))));
        }
        h1s[t] = fmaxf(a, 0.f);
    }
    __syncthreads();

    // h2: col = t&255, k-half = t>>8
    {
        const int col = t & 255, hf = t >> 8;
        const float4* w4 = (const float4*)(W2 + (size_t)col*CC1 + hf*256);
        const float4* v4 = (const float4*)(h1s + hf*256);
        float a = hf ? 0.f : b2[col];
        for (int q = 0; q < 64; ++q) {
            const float4 wv = w4[q];
            const float4 v  = v4[q];
            a = fmaf(wv.x,v.x, fmaf(wv.y,v.y, fmaf(wv.z,v.z, fmaf(wv.w,v.w, a))));
        }
        h2p[hf][col] = a;
    }
    __syncthreads();

    // out: logit = sum_col W3[col]*relu(h2)
    if (t < 256) {
        const float h2 = fmaxf(h2p[0][t] + h2p[1][t], 0.f);
        red[t] = W3[t] * h2;
    }
    __syncthreads();
    for (int s = 128; s > 0; s >>= 1) {
        if (t < s) red[t] += red[t + s];
        __syncthreads();
    }
    if (t == 0) out[b] = 1.f / (1.f + expf(-(red[0] + b3[0])));
}

// ===========================================================================
// Fallback (proven round-4 pipeline) for small workspace
// ===========================================================================
template<int USEBF>
__global__ __launch_bounds__(256, 4) void k_chain(
    const int* __restrict__ start_ids, const int* __restrict__ end_ids,
    const int* __restrict__ module_ids, const float* __restrict__ embed,
    const float* __restrict__ W, const unsigned short* __restrict__ Wt,
    const float* __restrict__ bvec, float* __restrict__ feat)
{
    const int t = threadIdx.x;
    const int p = t >> 7;
    const int o = t & 127;
    const int bp = blockIdx.x*2 + p;
    __shared__ float sx[2][2][EE];
    __shared__ float sy[2][2][EE];

    sx[p][0][o] = embed[(size_t)start_ids[bp]*EE + o];
    sy[p][0][o] = embed[(size_t)end_ids[bp]*EE + o];
    __syncthreads();

    int cur = 0;
    for (int l = 0; l < LL; ++l) {
        const int mid = module_ids[bp*LL + l];
        float ax = bvec[(size_t)mid*EE + o];
        float ay = ax;
        const float4* wr = (const float4*)(W + ((size_t)mid*EE + o)*EE);
        #pragma unroll
        for (int i = 0; i < EE; i += 4) {
            const float4 wv = wr[i >> 2];
            const float4 xv = *(const float4*)&sx[p][cur][i];
            const float4 yv = *(const float4*)&sy[p][cur][i];
            ax = fmaf(wv.x, xv.x, ax); ay = fmaf(wv.x, yv.x, ay);
            ax = fmaf(wv.y, xv.y, ax); ay = fmaf(wv.y, yv.y, ay);
            ax = fmaf(wv.z, xv.z, ax); ay = fmaf(wv.z, yv.z, ay);
            ax = fmaf(wv.w, xv.w, ax); ay = fmaf(wv.w, yv.w, ay);
        }
        sx[p][cur^1][o] = ax;
        sy[p][cur^1][o] = ay;
        __syncthreads();
        cur ^= 1;
    }

    feat[(size_t)bp*(2*EE) + o]      = sx[p][cur][o];
    feat[(size_t)bp*(2*EE) + EE + o] = sy[p][cur][o];
}

__global__ __launch_bounds__(256) void k_mlp(
    const int* __restrict__ counts, const float* __restrict__ state,
    const float* __restrict__ W1, const float* __restrict__ b1,
    const float* __restrict__ W2, const float* __restrict__ b2,
    const float* __restrict__ W3, const float* __restrict__ b3,
    float* __restrict__ out)
{
    const int t = threadIdx.x;
    const int b0 = blockIdx.x * 2;
    __shared__ float pl[2][256];
    __shared__ float h1s[2][CC1];
    __shared__ float h2s[2][CC2];
    __shared__ float red[256];

    #pragma unroll
    for (int r = 0; r < 2; ++r) {
        const int b = b0 + r;
        float acc = 0.f, cs = 0.f;
        #pragma unroll
        for (int p = 0; p < PP; ++p) {
            const float cc = (float)counts[b*PP + p];
            cs += cc;
            acc = fmaf(cc, state[((size_t)(b*PP + p))*256 + t], acc);
        }
        pl[r][t] = acc / cs;
    }
    __syncthreads();

    #pragma unroll
    for (int hh = 0; hh < 2; ++hh) {
        const int col = t + hh*256;
        const float4* w4 = (const float4*)(W1 + (size_t)col*256);
        float a0 = b1[col], a1 = a0;
        for (int q = 0; q < 64; ++q) {
            const float4 wv = w4[q];
            const float4 v0 = ((const float4*)pl[0])[q];
            const float4 v1 = ((const float4*)pl[1])[q];
            a0 = fmaf(wv.x,v0.x, fmaf(wv.y,v0.y, fmaf(wv.z,v0.z, fmaf(wv.w,v0.w, a0))));
            a1 = fmaf(wv.x,v1.x, fmaf(wv.y,v1.y, fmaf(wv.z,v1.z, fmaf(wv.w,v1.w, a1))));
        }
        h1s[0][col] = fmaxf(a0, 0.f);
        h1s[1][col] = fmaxf(a1, 0.f);
    }
    __syncthreads();

    {
        const float4* w4 = (const float4*)(W2 + (size_t)t*512);
        float a0 = b2[t], a1 = a0;
        for (int q = 0; q < 128; ++q) {
            const float4 wv = w4[q];
            const float4 v0 = ((const float4*)h1s[0])[q];
            const float4 v1 = ((const float4*)h1s[1])[q];
            a0 = fmaf(wv.x,v0.x, fmaf(wv.y,v0.y, fmaf(wv.z,v0.z, fmaf(wv.w,v0.w, a0))));
            a1 = fmaf(wv.x,v1.x, fmaf(wv.y,v1.y, fmaf(wv.z,v1.z, fmaf(wv.w,v1.w, a1))));
        }
        h2s[0][t] = fmaxf(a0, 0.f);
        h2s[1][t] = fmaxf(a1, 0.f);
    }
    __syncthreads();

    {
        const int r = t >> 7, k = t & 127;
        red[t] = fmaf(W3[k], h2s[r][k], W3[k+128] * h2s[r][k+128]);
        for (int s = 64; s > 0; s >>= 1) {
            __syncthreads();
            if ((t & 127) < s) red[t] += red[t + s];
        }
        __syncthreads();
        if ((t & 127) == 0)
            out[b0 + r] = 1.f / (1.f + expf(-(red[t] + b3[0])));
    }
}

// ---------------------------------------------------------------------------
extern "C" void kernel_launch(void* const* d_in, const int* in_sizes, int n_in,
                              void* d_out, int out_size, void* d_ws, size_t ws_size,
                              hipStream_t stream)
{
    const int*   start_ids  = (const int*)d_in[0];
    const int*   end_ids    = (const int*)d_in[1];
    const int*   module_ids = (const int*)d_in[2];
    const int*   counts     = (const int*)d_in[3];
    const float* embed      = (const float*)d_in[4];
    const float* W          = (const float*)d_in[5];
    const float* bvec       = (const float*)d_in[6];
    const float* W1         = (const float*)d_in[7];
    const float* b1         = (const float*)d_in[8];
    const float* W2         = (const float*)d_in[9];
    const float* b2         = (const float*)d_in[10];
    const float* W3         = (const float*)d_in[11];
    const float* b3         = (const float*)d_in[12];
    float* out  = (float*)d_out;
    char*  ws   = (char*)d_ws;

    if (ws_size >= (size_t)(NMOD*EE*EE*2)) {
        unsigned short* Wt = (unsigned short*)(ws + WS_WT);
        k_wtrans<<<4096, 256, 0, stream>>>(W, Wt);
        k_row<<<BB, 512, 0, stream>>>(start_ids, end_ids, module_ids, counts,
                                      embed, Wt, bvec, W1, b1, W2, b2, W3, b3,
                                      out);
    } else {
        float* feat = (float*)ws;   // needs 4 MB
        k_chain<0><<<NPATH/2, 256, 0, stream>>>(start_ids, end_ids, module_ids,
                                                embed, W, (const unsigned short*)0,
                                                bvec, feat);
        k_mlp<<<BB/2, 256, 0, stream>>>(counts, feat, W1, b1, W2, b2, W3, b3, out);
    }
}